// Round 12
// baseline (486.060 us; speedup 1.0000x reference)
//
#include <hip/hip_runtime.h>

#define NN 100000
#define NE 1600000

// bucketing for single-pass CSR sort
#define BSH 9                      // 512 nodes per bucket
#define BSZ (1 << BSH)
#define NB  196                    // ceil(NN / 512)
#define CHUNK 6250                 // NE / 256

// folded-weight buffer layout (float offsets)
#define OFF_C0   0
#define OFF_D0   64
#define OFF_WPL0 80
#define OFF_BPL0 6224
#define OFF_C1   6288
#define OFF_D1   6544
#define OFF_WPL1 6608
#define OFF_BPL1 31184
#define WBUF_TOT 31248

// transposed bf16 B-matrix buffer layout (ushort offsets)
#define BT1_OFF 0          // WPL1^T  [64][384]
#define BT0_OFF 24576      // WPL0^T  [64][96]
#define BTA_OFF 30720      // Wpre1A^T [64][64]
#define BTB_OFF 34816      // Wpre1B^T [64][64]
#define BT_TOT  38912
#define PREP_TOT (WBUF_TOT + BT_TOT)   // 70160

// ---- bf16 helpers (RNE pack, cheap unpack) ----
__device__ inline unsigned short pack_bf16(float a) {
  unsigned ua = __float_as_uint(a);
  ua += 0x7fffu + ((ua >> 16) & 1u);
  return (unsigned short)(ua >> 16);
}
__device__ inline float bf_s(unsigned short u) { return __uint_as_float(((unsigned)u) << 16); }

// ---------------- weight folding + direct Bt transposes ----------------
__global__ void k_prep(const float* __restrict__ We0, const float* __restrict__ be0,
                       const float* __restrict__ Wpre0, const float* __restrict__ bpre0,
                       const float* __restrict__ Wpost0, const float* __restrict__ bpost0,
                       const float* __restrict__ Wlin0, const float* __restrict__ blin0,
                       const float* __restrict__ We1, const float* __restrict__ be1,
                       const float* __restrict__ Wpre1, const float* __restrict__ bpre1,
                       const float* __restrict__ Wpost1, const float* __restrict__ bpost1,
                       const float* __restrict__ Wlin1, const float* __restrict__ blin1,
                       float* __restrict__ wbuf, unsigned short* __restrict__ Bt) {
  int id = blockIdx.x * 256 + threadIdx.x;
  if (id >= PREP_TOT) return;
  if (id < WBUF_TOT) {
    float a = 0.f;
    if (id < OFF_D0) {
      int j = id >> 4, f = id & 15;
      for (int t = 0; t < 16; t++) a = fmaf(We0[j*16+t], Wpre0[(32+t)*16+f], a);
    } else if (id < OFF_WPL0) {
      int f = id - OFF_D0; a = bpre0[f];
      for (int t = 0; t < 16; t++) a = fmaf(be0[t], Wpre0[(32+t)*16+f], a);
    } else if (id < OFF_BPL0) {
      int r = id - OFF_WPL0; int k = r >> 6, o = r & 63;
      for (int j = 0; j < 64; j++) a = fmaf(Wpost0[k*64+j], Wlin0[j*64+o], a);
    } else if (id < OFF_C1) {
      int o = id - OFF_BPL0; a = blin0[o];
      for (int j = 0; j < 64; j++) a = fmaf(bpost0[j], Wlin0[j*64+o], a);
    } else if (id < OFF_D1) {
      int r = id - OFF_C1; int j = r >> 6, f = r & 63;
      for (int t = 0; t < 64; t++) a = fmaf(We1[j*64+t], Wpre1[(128+t)*64+f], a);
    } else if (id < OFF_WPL1) {
      int f = id - OFF_D1; a = bpre1[f];
      for (int t = 0; t < 64; t++) a = fmaf(be1[t], Wpre1[(128+t)*64+f], a);
    } else if (id < OFF_BPL1) {
      int r = id - OFF_WPL1; int k = r >> 6, o = r & 63;
      for (int j = 0; j < 64; j++) a = fmaf(Wpost1[k*64+j], Wlin1[j*64+o], a);
    } else {
      int o = id - OFF_BPL1; a = blin1[o];
      for (int j = 0; j < 64; j++) a = fmaf(bpost1[j], Wlin1[j*64+o], a);
    }
    wbuf[id] = a;
    return;
  }
  int rid = id - WBUF_TOT;
  if (rid < 24576) {                       // Bt1[nn][k] = (Wpost1@Wlin1)^T
    int nn = rid / 384, k = rid - nn * 384;
    float a = 0.f;
    for (int j = 0; j < 64; j++) a = fmaf(Wpost1[k*64+j], Wlin1[j*64+nn], a);
    Bt[BT1_OFF + rid] = pack_bf16(a);
  } else if (rid < 30720) {                // Bt0[nn][k] = (Wpost0@Wlin0)^T
    int r2 = rid - 24576;
    int nn = r2 / 96, k = r2 - nn * 96;
    float a = 0.f;
    for (int j = 0; j < 64; j++) a = fmaf(Wpost0[k*64+j], Wlin0[j*64+nn], a);
    Bt[BT0_OFF + r2] = pack_bf16(a);
  } else if (rid < 34816) {                // BtA[nn][k] = Wpre1[0:64]^T
    int r3 = rid - 30720;
    int nn = r3 >> 6, k = r3 & 63;
    Bt[BTA_OFF + r3] = pack_bf16(Wpre1[k*64+nn]);
  } else {                                 // BtB[nn][k] = Wpre1[64:128]^T
    int r4 = rid - 34816;
    int nn = r4 >> 6, k = r4 & 63;
    Bt[BTB_OFF + r4] = pack_bf16(Wpre1[(64+k)*64+nn]);
  }
}

// ---------------- bucket histogram (196 counters, LDS-aggregated) ----------------
__global__ __launch_bounds__(256) void k_bcnt(const int* __restrict__ dst,
                                              int* __restrict__ bcnt) {
  __shared__ int h[NB];
  for (int b = threadIdx.x; b < NB; b += 256) h[b] = 0;
  __syncthreads();
  const int lo = blockIdx.x * CHUNK, hi = lo + CHUNK;
  for (int i = lo + threadIdx.x; i < hi; i += 256)
    atomicAdd(&h[dst[i] >> BSH], 1);
  __syncthreads();
  for (int b = threadIdx.x; b < NB; b += 256)
    if (h[b]) atomicAdd(&bcnt[b], h[b]);
}

// scan 196 bucket counts -> gbase[0..NB] (exclusive, gbase[NB]=NE) + gfill copy
__global__ void k_bscan(const int* __restrict__ bcnt, int* __restrict__ gbase,
                        int* __restrict__ gfill) {
  __shared__ int lds[256];
  int t = threadIdx.x;
  int v = (t < NB) ? bcnt[t] : 0;
  lds[t] = v;
  __syncthreads();
  for (int off = 1; off < 256; off <<= 1) {
    int u = (t >= off) ? lds[t - off] : 0;
    __syncthreads();
    lds[t] += u;
    __syncthreads();
  }
  if (t <= NB) {
    int excl = (t == 0) ? 0 : lds[t - 1];
    gbase[t] = excl;
    if (t < NB) gfill[t] = excl;
  }
}

// coarse sort: sequential edge read (dst,src,ea) -> 16B records in bucket runs
__global__ __launch_bounds__(256) void k_bin16(const int* __restrict__ dst,
                                               const int* __restrict__ src,
                                               const float4* __restrict__ ea,
                                               int* __restrict__ gfill,
                                               int4* __restrict__ rec) {
  __shared__ int hcnt[NB];
  __shared__ int hbase[NB];
  const int t = threadIdx.x;
  for (int b = t; b < NB; b += 256) hcnt[b] = 0;
  __syncthreads();
  const int lo = blockIdx.x * CHUNK, hi = lo + CHUNK;
  for (int i = lo + t; i < hi; i += 256)
    atomicAdd(&hcnt[dst[i] >> BSH], 1);
  __syncthreads();
  for (int b = t; b < NB; b += 256) {
    int c = hcnt[b];
    hbase[b] = c > 0 ? atomicAdd(&gfill[b], c) : 0;
    hcnt[b] = 0;
  }
  __syncthreads();
  for (int i = lo + t; i < hi; i += 256) {
    int d = dst[i];
    int b = d >> BSH;
    int lp = atomicAdd(&hcnt[b], 1);
    float4 e = ea[i];                       // sequential 16B read
    int4 r;
    r.x = d; r.y = src[i];
    r.z = (int)(((unsigned)pack_bf16(e.y) << 16) | (unsigned)pack_bf16(e.x));
    r.w = (int)(((unsigned)pack_bf16(e.w) << 16) | (unsigned)pack_bf16(e.z));
    rec[hbase[b] + lp] = r;
  }
}

// per-bucket: LDS degree histogram -> scan -> rowptr; scatter col+eapb into
// the bucket's L2-resident windows.
__global__ __launch_bounds__(256) void k_scatter2b(const int4* __restrict__ rec,
                                                   const int* __restrict__ gbase,
                                                   int* __restrict__ rowptr,
                                                   int* __restrict__ col,
                                                   ushort4* __restrict__ eapb) {
  __shared__ int cnt[BSZ];
  __shared__ int scn[BSZ];
  __shared__ int fill[BSZ];
  const int b = blockIdx.x;
  const int n0 = b << BSH;
  const int n1 = (n0 + BSZ < NN) ? n0 + BSZ : NN;
  const int t = threadIdx.x;
  cnt[t] = 0; cnt[t + 256] = 0;
  __syncthreads();
  const int base = gbase[b];
  const int total = gbase[b + 1] - base;
  for (int i = t; i < total; i += 256)
    atomicAdd(&cnt[rec[base + i].x - n0], 1);
  __syncthreads();
  scn[t] = cnt[t]; scn[t + 256] = cnt[t + 256];
  __syncthreads();
  for (int off = 1; off < BSZ; off <<= 1) {
    int v0 = (t >= off) ? scn[t - off] : 0;
    int i1 = t + 256;
    int v1 = (i1 >= off) ? scn[i1 - off] : 0;
    __syncthreads();
    scn[t] += v0; scn[i1] += v1;
    __syncthreads();
  }
  {
    int e0 = scn[t] - cnt[t];
    int e1 = scn[t + 256] - cnt[t + 256];
    fill[t] = base + e0; fill[t + 256] = base + e1;
    if (n0 + t < n1) rowptr[n0 + t] = base + e0;
    if (n0 + t + 256 < n1) rowptr[n0 + t + 256] = base + e1;
  }
  if (b == NB - 1 && t == 0) rowptr[NN] = base + total;
  __syncthreads();
  for (int i = t; i < total; i += 256) {
    int4 r = rec[base + i];
    int pos = atomicAdd(&fill[r.x - n0], 1);
    col[pos] = r.y;
    ushort4 e;
    e.x = (unsigned short)(r.z & 0xffff);
    e.y = (unsigned short)((unsigned)r.z >> 16);
    e.z = (unsigned short)(r.w & 0xffff);
    e.w = (unsigned short)((unsigned)r.w >> 16);
    eapb[pos] = e;
  }
}

// ---------------- layer 0 node pre-projection ----------------
__global__ void k_pre0(const float* __restrict__ x, const float* __restrict__ Wpre0,
                       float* __restrict__ xA0, unsigned short* __restrict__ xB0b) {
  int t = blockIdx.x * 256 + threadIdx.x;   // NN*32 threads
  int node = t >> 5, k = t & 31;
  int f = k & 15;
  const float* W = Wpre0 + (k < 16 ? 0 : 256);
  const float* xr = x + (size_t)node * 16;
  float a = 0.f;
#pragma unroll
  for (int j = 0; j < 16; j++) a = fmaf(xr[j], W[j*16+f], a);
  if (k < 16) xA0[(size_t)node*16+f] = a;
  else        xB0b[(size_t)node*16+f] = pack_bf16(a);
}

// ---------------- layer 0 aggregation: one node per 64-thread block ----------------
// node = blockIdx.x uniform -> col/eapb meta become scalar loads; lane u=lane>>4
// handles edge slot u, f=lane&15 the feature; 8 edges/iter = 2 gathers in flight.
__global__ __launch_bounds__(64) void k_agg0(const float* __restrict__ x,
                                             const float* __restrict__ xA0,
                                             const unsigned short* __restrict__ xB0b,
                                             const int* __restrict__ rowptr,
                                             const int* __restrict__ col,
                                             const ushort4* __restrict__ eapb,
                                             const float* __restrict__ wbuf,
                                             unsigned short* __restrict__ vec96b) {
  const int lane = threadIdx.x;
  const int u = lane >> 4, f = lane & 15;
  const int node = blockIdx.x;
  const int start = rowptr[node], end = rowptr[node + 1];
  const int cnt = end - start;
  const float c0 = wbuf[OFF_C0 + f],      c1v = wbuf[OFF_C0 + 16 + f];
  const float c2v = wbuf[OFF_C0 + 32 + f], c3v = wbuf[OFF_C0 + 48 + f];
  float s = 0.f, sq = 0.f, mx = -__builtin_inff(), mn = __builtin_inff();
  const int e1 = end - 1;
  for (int p = start; p < end; p += 8) {
    int pa = p + u, pb = p + 4 + u;
    // scalar meta (uniform addresses)
    int ca0 = col[min(p + 0, e1)], ca1 = col[min(p + 1, e1)];
    int ca2 = col[min(p + 2, e1)], ca3 = col[min(p + 3, e1)];
    int cb0 = col[min(p + 4, e1)], cb1 = col[min(p + 5, e1)];
    int cb2 = col[min(p + 6, e1)], cb3 = col[min(p + 7, e1)];
    ushort4 ea0 = eapb[min(p + 0, e1)], ea1 = eapb[min(p + 1, e1)];
    ushort4 ea2 = eapb[min(p + 2, e1)], ea3 = eapb[min(p + 3, e1)];
    ushort4 eb0 = eapb[min(p + 4, e1)], eb1 = eapb[min(p + 5, e1)];
    ushort4 eb2 = eapb[min(p + 6, e1)], eb3 = eapb[min(p + 7, e1)];
    int sa = u < 2 ? (u == 0 ? ca0 : ca1) : (u == 2 ? ca2 : ca3);
    int sb = u < 2 ? (u == 0 ? cb0 : cb1) : (u == 2 ? cb2 : cb3);
    float va = bf_s(xB0b[(size_t)sa * 16 + f]);
    float vb = bf_s(xB0b[(size_t)sb * 16 + f]);
    ushort4 eA = u < 2 ? (u == 0 ? ea0 : ea1) : (u == 2 ? ea2 : ea3);
    ushort4 eB = u < 2 ? (u == 0 ? eb0 : eb1) : (u == 2 ? eb2 : eb3);
    va = fmaf(bf_s(eA.x), c0, va); va = fmaf(bf_s(eA.y), c1v, va);
    va = fmaf(bf_s(eA.z), c2v, va); va = fmaf(bf_s(eA.w), c3v, va);
    vb = fmaf(bf_s(eB.x), c0, vb); vb = fmaf(bf_s(eB.y), c1v, vb);
    vb = fmaf(bf_s(eB.z), c2v, vb); vb = fmaf(bf_s(eB.w), c3v, vb);
    bool oka = pa < end, okb = pb < end;
    s += oka ? va : 0.f; s += okb ? vb : 0.f;
    sq = oka ? fmaf(va, va, sq) : sq;
    sq = okb ? fmaf(vb, vb, sq) : sq;
    mx = oka ? fmaxf(mx, va) : mx; mx = okb ? fmaxf(mx, vb) : mx;
    mn = oka ? fminf(mn, va) : mn; mn = okb ? fminf(mn, vb) : mn;
  }
  s  += __shfl_xor(s, 16);  s  += __shfl_xor(s, 32);
  sq += __shfl_xor(sq, 16); sq += __shfl_xor(sq, 32);
  mx = fmaxf(mx, __shfl_xor(mx, 16)); mx = fmaxf(mx, __shfl_xor(mx, 32));
  mn = fminf(mn, __shfl_xor(mn, 16)); mn = fminf(mn, __shfl_xor(mn, 32));
  if (u == 0) {
    const float c = xA0[(size_t)node * 16 + f] + wbuf[OFF_D0 + f];
    float sum_m, mean_m, mx_m, mn_m, std_m;
    if (cnt > 0) {
      float inv = 1.f / (float)cnt;
      float meanv = s * inv;
      sum_m = fmaf((float)cnt, c, s);
      mean_m = meanv + c;
      mx_m = mx + c; mn_m = mn + c;
      float var = fmaf(-meanv, meanv, sq * inv);
      std_m = sqrtf(fmaxf(var, 0.f) + 1e-5f);
    } else {
      sum_m = 0.f; mean_m = 0.f; mx_m = 0.f; mn_m = 0.f; std_m = sqrtf(1e-5f);
    }
    unsigned short* vr = vec96b + (size_t)node * 96;
    vr[f]      = pack_bf16(x[(size_t)node * 16 + f]);
    vr[16 + f] = pack_bf16(sum_m);
    vr[32 + f] = pack_bf16(mean_m);
    vr[48 + f] = pack_bf16(mx_m);
    vr[64 + f] = pack_bf16(mn_m);
    vr[80 + f] = pack_bf16(std_m);
  }
}

// ---------------- layer 1 aggregation: one node per 64-thread block ----------------
__global__ __launch_bounds__(64) void k_agg1(const unsigned short* __restrict__ xA1b,
                                             const unsigned short* __restrict__ xB1b,
                                             const int* __restrict__ rowptr,
                                             const int* __restrict__ col,
                                             const ushort4* __restrict__ eapb,
                                             const float* __restrict__ wbuf,
                                             unsigned short* __restrict__ agg320b) {
  const int f = threadIdx.x;            // 0..63
  const int node = blockIdx.x;
  const int start = rowptr[node], end = rowptr[node + 1];
  const int cnt = end - start;
  const float c0 = wbuf[OFF_C1 + f],       c1v = wbuf[OFF_C1 + 64 + f];
  const float c2v = wbuf[OFF_C1 + 128 + f], c3v = wbuf[OFF_C1 + 192 + f];
  float s = 0.f, sq = 0.f, mx = -__builtin_inff(), mn = __builtin_inff();
  int p = start;
  for (; p + 7 < end; p += 8) {
#pragma unroll
    for (int u = 0; u < 8; u++) {
      int si = col[p + u];                                   // scalar load
      ushort4 e = eapb[p + u];                               // scalar dwordx2
      const unsigned short* row = xB1b + (unsigned)si * 64;  // SALU base
      float v = bf_s(row[f]);                                // 128B coalesced gather
      v = fmaf(bf_s(e.x), c0, v); v = fmaf(bf_s(e.y), c1v, v);
      v = fmaf(bf_s(e.z), c2v, v); v = fmaf(bf_s(e.w), c3v, v);
      s += v; sq = fmaf(v, v, sq); mx = fmaxf(mx, v); mn = fminf(mn, v);
    }
  }
  for (; p < end; p++) {
    int si = col[p];
    ushort4 e = eapb[p];
    const unsigned short* row = xB1b + (unsigned)si * 64;
    float v = bf_s(row[f]);
    v = fmaf(bf_s(e.x), c0, v); v = fmaf(bf_s(e.y), c1v, v);
    v = fmaf(bf_s(e.z), c2v, v); v = fmaf(bf_s(e.w), c3v, v);
    s += v; sq = fmaf(v, v, sq); mx = fmaxf(mx, v); mn = fminf(mn, v);
  }
  const float c = bf_s(xA1b[(size_t)node * 64 + f]) + wbuf[OFF_D1 + f];
  float sum_m, mean_m, mx_m, mn_m, std_m;
  if (cnt > 0) {
    float inv = 1.f / (float)cnt;
    float meanv = s * inv;
    sum_m = fmaf((float)cnt, c, s);
    mean_m = meanv + c;
    mx_m = mx + c; mn_m = mn + c;
    float var = fmaf(-meanv, meanv, sq * inv);
    std_m = sqrtf(fmaxf(var, 0.f) + 1e-5f);
  } else {
    sum_m = 0.f; mean_m = 0.f; mx_m = 0.f; mn_m = 0.f; std_m = sqrtf(1e-5f);
  }
  unsigned short* ar = agg320b + (size_t)node * 320;
  ar[f]       = pack_bf16(sum_m);
  ar[64 + f]  = pack_bf16(mean_m);
  ar[128 + f] = pack_bf16(mx_m);
  ar[192 + f] = pack_bf16(mn_m);
  ar[256 + f] = pack_bf16(std_m);
}

// ---------------- MFMA GEMM: C[n,64] = (relu)(A[n,K]_bf16 @ Bt^T + bias) ----------------
template <int K, bool RELU, int OMODE>
__global__ __launch_bounds__(256) void k_mmf(const unsigned short* __restrict__ A,
                                             const unsigned short* __restrict__ Bt,
                                             const float* __restrict__ bias,
                                             void* __restrict__ C, int n) {
  using bf16x8 = __attribute__((ext_vector_type(8))) short;
  using f32x4  = __attribute__((ext_vector_type(4))) float;
  const int wave = threadIdx.x >> 6, lane = threadIdx.x & 63;
  const int qm = lane & 15, quad = lane >> 4;
  const int m0 = blockIdx.x * 64 + wave * 16;
  const int mrow = m0 + qm;
  f32x4 acc[4] = {};
#pragma unroll
  for (int k0 = 0; k0 < K; k0 += 32) {
    bf16x8 a = *(const bf16x8*)(A + (size_t)mrow * K + k0 + quad * 8);
#pragma unroll
    for (int nt = 0; nt < 4; nt++) {
      bf16x8 b = *(const bf16x8*)(Bt + (size_t)(nt * 16 + qm) * K + k0 + quad * 8);
      acc[nt] = __builtin_amdgcn_mfma_f32_16x16x32_bf16(a, b, acc[nt], 0, 0, 0);
    }
  }
#pragma unroll
  for (int nt = 0; nt < 4; nt++) {
    int colc = nt * 16 + qm;
    float bb = bias ? bias[colc] : 0.f;
#pragma unroll
    for (int r = 0; r < 4; r++) {
      int m = m0 + quad * 4 + r;
      if (m < n) {
        float v = acc[nt][r] + bb;
        if (RELU) v = fmaxf(v, 0.f);
        if (OMODE == 0) ((float*)C)[(size_t)m * 64 + colc] = v;
        else ((unsigned short*)C)[(size_t)m * 64 + colc] = pack_bf16(v);
      }
    }
  }
}

// ---------------- dual-B MFMA: xA1b + xB1b (both bf16) from one pass over hb ----------------
__global__ __launch_bounds__(256) void k_mmf64d(const unsigned short* __restrict__ A,
                                                const unsigned short* __restrict__ BtA,
                                                const unsigned short* __restrict__ BtB,
                                                unsigned short* __restrict__ xA1b,
                                                unsigned short* __restrict__ xB1b, int n) {
  using bf16x8 = __attribute__((ext_vector_type(8))) short;
  using f32x4  = __attribute__((ext_vector_type(4))) float;
  const int wave = threadIdx.x >> 6, lane = threadIdx.x & 63;
  const int qm = lane & 15, quad = lane >> 4;
  const int m0 = blockIdx.x * 64 + wave * 16;
  const int mrow = m0 + qm;
  f32x4 accA[4] = {}, accB[4] = {};
#pragma unroll
  for (int k0 = 0; k0 < 64; k0 += 32) {
    bf16x8 a = *(const bf16x8*)(A + (size_t)mrow * 64 + k0 + quad * 8);
#pragma unroll
    for (int nt = 0; nt < 4; nt++) {
      bf16x8 bA = *(const bf16x8*)(BtA + (size_t)(nt * 16 + qm) * 64 + k0 + quad * 8);
      bf16x8 bB = *(const bf16x8*)(BtB + (size_t)(nt * 16 + qm) * 64 + k0 + quad * 8);
      accA[nt] = __builtin_amdgcn_mfma_f32_16x16x32_bf16(a, bA, accA[nt], 0, 0, 0);
      accB[nt] = __builtin_amdgcn_mfma_f32_16x16x32_bf16(a, bB, accB[nt], 0, 0, 0);
    }
  }
#pragma unroll
  for (int nt = 0; nt < 4; nt++) {
    int colc = nt * 16 + qm;
#pragma unroll
    for (int r = 0; r < 4; r++) {
      int m = m0 + quad * 4 + r;
      if (m < n) {
        xA1b[(size_t)m * 64 + colc] = pack_bf16(accA[nt][r]);
        xB1b[(size_t)m * 64 + colc] = pack_bf16(accB[nt][r]);
      }
    }
  }
}

// ---------------- fused: h2 = relu([hb|aggb]@Bt1^T + bias); hgsb = bf16((h2@Wg)*dinv) ----
__global__ __launch_bounds__(256) void k_mm384g(const unsigned short* __restrict__ hb,
                                                const unsigned short* __restrict__ aggb,
                                                const unsigned short* __restrict__ Bt1,
                                                const float* __restrict__ wbuf,
                                                const float* __restrict__ Wg,
                                                const int* __restrict__ rowptr,
                                                unsigned short* __restrict__ hgsb,
                                                float* __restrict__ dinv, int n) {
  using bf16x8 = __attribute__((ext_vector_type(8))) short;
  using f32x4  = __attribute__((ext_vector_type(4))) float;
  __shared__ float h2t[4][16][65];     // padded: stride 65 breaks bank conflicts
  __shared__ float wg[64][16];
  const int tid = threadIdx.x;
  for (int i = tid; i < 1024; i += 256) wg[i >> 4][i & 15] = Wg[i];
  const int wave = tid >> 6, lane = tid & 63;
  const int qm = lane & 15, quad = lane >> 4;
  const int m0 = blockIdx.x * 64 + wave * 16;
  const int mrow = m0 + qm;
  f32x4 acc[4] = {};
  for (int k0 = 0; k0 < 384; k0 += 32) {
    bf16x8 a;
    if (k0 < 64) a = *(const bf16x8*)(hb + (size_t)mrow * 64 + k0 + quad * 8);
    else         a = *(const bf16x8*)(aggb + (size_t)mrow * 320 + (k0 - 64) + quad * 8);
#pragma unroll
    for (int nt = 0; nt < 4; nt++) {
      bf16x8 b = *(const bf16x8*)(Bt1 + (size_t)(nt * 16 + qm) * 384 + k0 + quad * 8);
      acc[nt] = __builtin_amdgcn_mfma_f32_16x16x32_bf16(a, b, acc[nt], 0, 0, 0);
    }
  }
#pragma unroll
  for (int nt = 0; nt < 4; nt++) {
    int colc = nt * 16 + qm;
    float bias = wbuf[OFF_BPL1 + colc];
#pragma unroll
    for (int r = 0; r < 4; r++)
      h2t[wave][quad * 4 + r][colc] = fmaxf(acc[nt][r] + bias, 0.f);
  }
  __syncthreads();
  const int row = lane & 15, g = lane >> 4;
  float hg0 = 0.f, hg1 = 0.f, hg2 = 0.f, hg3 = 0.f;
#pragma unroll 16
  for (int j = 0; j < 64; j++) {
    float hv = h2t[wave][row][j];
    float4 w4 = *(const float4*)&wg[j][g * 4];
    hg0 = fmaf(hv, w4.x, hg0); hg1 = fmaf(hv, w4.y, hg1);
    hg2 = fmaf(hv, w4.z, hg2); hg3 = fmaf(hv, w4.w, hg3);
  }
  int m = m0 + row;
  if (m < n) {
    int deg = rowptr[m + 1] - rowptr[m] + 1;   // +1 self loop
    float dv = 1.0f / sqrtf((float)deg);
    if (g == 0) dinv[m] = dv;
    ushort4 pk;
    pk.x = pack_bf16(hg0 * dv); pk.y = pack_bf16(hg1 * dv);
    pk.z = pack_bf16(hg2 * dv); pk.w = pack_bf16(hg3 * dv);
    *(ushort4*)(hgsb + (size_t)m * 16 + g * 4) = pk;
  }
}

// ---------------- GCN aggregate + MLP head: one node per 64-thread block ----------------
// Scalar col meta + 8-edge unroll: 2 independent gather chains/lane.
__global__ __launch_bounds__(64) void k_head(const float* __restrict__ x,
                                             const unsigned short* __restrict__ hgsb,
                                             const float* __restrict__ dinv,
                                             const int* __restrict__ rowptr,
                                             const int* __restrict__ col,
                                             const float* __restrict__ bg,
                                             const float* __restrict__ Wh1,
                                             const float* __restrict__ bh1,
                                             const float* __restrict__ Wh2,
                                             const float* __restrict__ bh2,
                                             float* __restrict__ out) {
  __shared__ float zb[32];
  __shared__ float o1b[10];
  const int lane = threadIdx.x;
  const int u = lane >> 4, f = lane & 15;
  const int node = blockIdx.x;
  const int start = rowptr[node], end = rowptr[node + 1];
  float s = 0.f;
  const int e1 = end - 1;
  for (int p = start; p < end; p += 8) {
    int ca0 = col[min(p + 0, e1)], ca1 = col[min(p + 1, e1)];
    int ca2 = col[min(p + 2, e1)], ca3 = col[min(p + 3, e1)];
    int cb0 = col[min(p + 4, e1)], cb1 = col[min(p + 5, e1)];
    int cb2 = col[min(p + 6, e1)], cb3 = col[min(p + 7, e1)];
    int sa = u < 2 ? (u == 0 ? ca0 : ca1) : (u == 2 ? ca2 : ca3);
    int sb = u < 2 ? (u == 0 ? cb0 : cb1) : (u == 2 ? cb2 : cb3);
    float va = bf_s(hgsb[(size_t)sa * 16 + f]);
    float vb = bf_s(hgsb[(size_t)sb * 16 + f]);
    s += (p + u < end) ? va : 0.f;
    s += (p + 4 + u < end) ? vb : 0.f;
  }
  s += __shfl_xor(s, 16); s += __shfl_xor(s, 32);
  if (u == 0) {
    float gout = (s + bf_s(hgsb[(size_t)node * 16 + f])) * dinv[node] + bg[f];
    zb[f] = gout;
    zb[16 + f] = x[(size_t)node * 16 + f];
  }
  __syncthreads();
  if (lane < 10) {
    float a = bh1[lane];
#pragma unroll
    for (int k = 0; k < 32; k++) a = fmaf(zb[k], Wh1[k * 10 + lane], a);
    o1b[lane] = fmaxf(a, 0.f);
  }
  __syncthreads();
  if (lane < 10) {
    float a = bh2[lane];
#pragma unroll
    for (int j = 0; j < 10; j++) a = fmaf(o1b[j], Wh2[j * 10 + lane], a);
    out[(size_t)node * 10 + lane] = a;
  }
}

// ---------------- launcher ----------------
extern "C" void kernel_launch(void* const* d_in, const int* in_sizes, int n_in,
                              void* d_out, int out_size, void* d_ws, size_t ws_size,
                              hipStream_t stream) {
  const float* x      = (const float*)d_in[0];
  const int*   ei     = (const int*)d_in[1];
  const float* eattr  = (const float*)d_in[2];
  const float* We0    = (const float*)d_in[3];
  const float* be0    = (const float*)d_in[4];
  const float* Wpre0  = (const float*)d_in[5];
  const float* bpre0  = (const float*)d_in[6];
  const float* Wpost0 = (const float*)d_in[7];
  const float* bpost0 = (const float*)d_in[8];
  const float* Wlin0  = (const float*)d_in[9];
  const float* blin0  = (const float*)d_in[10];
  const float* We1    = (const float*)d_in[11];
  const float* be1    = (const float*)d_in[12];
  const float* Wpre1  = (const float*)d_in[13];
  const float* bpre1  = (const float*)d_in[14];
  const float* Wpost1 = (const float*)d_in[15];
  const float* bpost1 = (const float*)d_in[16];
  const float* Wlin1  = (const float*)d_in[17];
  const float* blin1  = (const float*)d_in[18];
  const float* Wg     = (const float*)d_in[19];
  const float* bg     = (const float*)d_in[20];
  const float* Wh1    = (const float*)d_in[21];
  const float* bh1    = (const float*)d_in[22];
  const float* Wh2    = (const float*)d_in[23];
  const float* bh2    = (const float*)d_in[24];
  const int* srcI = ei;
  const int* dstI = ei + NE;
  float* out = (float*)d_out;

  char* base = (char*)d_ws;
  size_t off = 0;
  auto take = [&](size_t bytes) -> char* {
    char* p = base + off;
    off += (bytes + 255) & ~(size_t)255;
    return p;
  };
  int* rowptr  = (int*)take((size_t)(NN + 1) * 4);
  int* bcnt    = (int*)take(256 * 4);
  int* gbase   = (int*)take(256 * 4);
  int* gfill   = (int*)take(256 * 4);
  unsigned short* Bt = (unsigned short*)take((size_t)BT_TOT * 2);
  int* col     = (int*)take((size_t)NE * 4);          // 6.4MB
  ushort4* eapb = (ushort4*)take((size_t)NE * 8);     // 12.8MB
  float* wbuf  = (float*)take((size_t)WBUF_TOT * 4);
  // rec16 (25.6MB) dies after scatter2b; xA1b/xB1b overlay it afterwards
  char* recbuf = take((size_t)NE * 16);
  int4* rec    = (int4*)recbuf;
  unsigned short* xA1b = (unsigned short*)recbuf;                       // 12.8MB
  unsigned short* xB1b = (unsigned short*)(recbuf + (size_t)NN * 64 * 2); // 12.8MB
  // region Z (128MB): vec96b/xA0/xB0b early -> agg320b [0,64) mid;
  // hgsb/dinv at +64MB (written by mm384g); hb at +96MB.
  char* Z = take((size_t)NN * 320 * 4);
  unsigned short* vec96b  = (unsigned short*)Z;                         // 19.2MB
  float* xA0    = (float*)(Z + (size_t)NN * 96 * 2);                    // 6.4MB
  unsigned short* xB0b = (unsigned short*)(Z + (size_t)NN * 96 * 2 + (size_t)NN * 16 * 4);
  unsigned short* agg320b = (unsigned short*)Z;                         // 64MB
  unsigned short* hgsb = (unsigned short*)(Z + (size_t)64 * 1024 * 1024); // 3.2MB
  float* dinv   = (float*)(Z + (size_t)64 * 1024 * 1024 + (size_t)NN * 16 * 2);
  unsigned short* hb = (unsigned short*)(Z + (size_t)96 * 1024 * 1024); // 12.8MB

  hipMemsetAsync(bcnt, 0, 256 * 4, stream);
  k_prep<<<(PREP_TOT + 255) / 256, 256, 0, stream>>>(
      We0, be0, Wpre0, bpre0, Wpost0, bpost0, Wlin0, blin0,
      We1, be1, Wpre1, bpre1, Wpost1, bpost1, Wlin1, blin1, wbuf, Bt);
  k_bcnt<<<256, 256, 0, stream>>>(dstI, bcnt);
  k_bscan<<<1, 256, 0, stream>>>(bcnt, gbase, gfill);
  k_bin16<<<256, 256, 0, stream>>>(dstI, srcI, (const float4*)eattr, gfill, rec);
  k_scatter2b<<<NB, 256, 0, stream>>>(rec, gbase, rowptr, col, eapb);
  k_pre0<<<NN * 32 / 256, 256, 0, stream>>>(x, Wpre0, xA0, xB0b);
  k_agg0<<<NN, 64, 0, stream>>>(x, xA0, xB0b, rowptr, col, eapb, wbuf, vec96b);
  k_mmf<96, true, 1><<<(NN + 63) / 64, 256, 0, stream>>>(
      vec96b, Bt + BT0_OFF, wbuf + OFF_BPL0, hb, NN);
  k_mmf64d<<<(NN + 63) / 64, 256, 0, stream>>>(
      hb, Bt + BTA_OFF, Bt + BTB_OFF, xA1b, xB1b, NN);
  k_agg1<<<NN, 64, 0, stream>>>(xA1b, xB1b, rowptr, col, eapb, wbuf, agg320b);
  k_mm384g<<<(NN + 63) / 64, 256, 0, stream>>>(
      hb, agg320b, Bt + BT1_OFF, wbuf, Wg, rowptr, hgsb, dinv, NN);
  k_head<<<NN, 64, 0, stream>>>(x, hgsb, dinv, rowptr, col, bg, Wh1, bh1,
                                Wh2, bh2, out);
}